// Round 6
// baseline (744.075 us; speedup 1.0000x reference)
//
#include <hip/hip_runtime.h>
#include <hip/hip_bf16.h>

// Problem constants (MinimalEventMamba)
#define BB   4
#define NBC  5
#define HD   64
#define NLAYER 4
#define NFC  10
#define DIM  128
#define DSN  16
#define DCN  4
#define DTRK 4
#define HH   64
#define WWD  64
#define LL   4096
#define MM   (BB*LL)
#define SUB    8           // sub-chunk length (rows per block) -> 2048 blocks = 8/CU
#define NSUB   512         // sub-chunks per batch
#define WIN    11          // SUB + 3 halo rows (xproj only)

// ---------------- prep: all weight transposes + zero stats ----------------
__global__ void k_prep_all(const float* __restrict__ in_proj, const float* __restrict__ out_proj,
                           const float* __restrict__ dec1_w, const float* __restrict__ dec2_w,
                           float* __restrict__ wTin, float* __restrict__ wTout,
                           float* __restrict__ wT1, float* __restrict__ wT2,
                           float* __restrict__ stats, float* __restrict__ stats2) {
    int idx = blockIdx.x * blockDim.x + threadIdx.x;
    if (idx < 65536) {
        int n = idx & 255, k = (idx >> 8) & 63, l = idx >> 14;
        wTin[idx] = in_proj[(l << 14) + (n << 6) + k];
    } else if (idx < 98304) {
        int j = idx - 65536;
        int n = j & 63, k = (j >> 6) & 127, l = j >> 13;
        wTout[j] = out_proj[(l << 13) + (n << 7) + k];
    } else if (idx < 135168) {
        int j = idx - 98304;
        int co = j & 63, tap = (j >> 6) % 9, ci = j / 576;
        wT1[j] = dec1_w[co * 576 + ci * 9 + tap];
    } else if (idx < 142848) {
        int j = idx - 135168;
        int tap = j % 12, t2 = j / 12, co = t2 % NFC, ci = t2 / NFC;
        wT2[j] = (tap < 9) ? dec2_w[co * 576 + ci * 9 + tap] : 0.f;
    } else if (idx < 143104) {
        int j = idx - 142848;
        if (j < 128) stats[j] = 0.f; else stats2[j - 128] = 0.f;
    }
}

// ---------------- Encoder conv + fused BN-stat partials ----------------
__global__ void k_enc_conv(const float* __restrict__ x, const float* __restrict__ w,
                           const float* __restrict__ bias, float* __restrict__ out,
                           float* __restrict__ stats) {
    __shared__ float r1[256], r2[256];
    int tid = threadIdx.x;
    int idx = blockIdx.x * 256 + tid;
    int wx = idx & 63;
    int hy = (idx >> 6) & 63;
    int co = (idx >> 12) & 63;
    int b  = idx >> 18;
    float acc = bias[co];
    for (int ci = 0; ci < NBC; ++ci) {
        const float* xin = x + (((long)(b * NBC + ci)) << 12);
        const float* wp  = w + (co * NBC + ci) * 9;
        #pragma unroll
        for (int kh = 0; kh < 3; ++kh) {
            int ih = hy + kh - 1;
            if (ih < 0 || ih >= HH) continue;
            #pragma unroll
            for (int kw = 0; kw < 3; ++kw) {
                int iw = wx + kw - 1;
                if (iw < 0 || iw >= WWD) continue;
                acc += xin[(ih << 6) + iw] * wp[kh * 3 + kw];
            }
        }
    }
    out[idx] = acc;
    r1[tid] = acc; r2[tid] = acc * acc;
    __syncthreads();
    for (int off = 128; off > 0; off >>= 1) {
        if (tid < off) { r1[tid] += r1[tid + off]; r2[tid] += r2[tid + off]; }
        __syncthreads();
    }
    if (tid == 0) {
        atomicAdd(&stats[co], r1[0]);
        atomicAdd(&stats[64 + co], r2[0]);
    }
}

// ---- in_proj GEMM (first layer) with FUSED BN+ReLU apply ----
__global__ __launch_bounds__(256, 1) void k_gemm_in_bn(const float* __restrict__ src,
                                                       const float* __restrict__ stats,
                                                       const float* __restrict__ g,
                                                       const float* __restrict__ be,
                                                       const float* __restrict__ wT,
                                                       float* __restrict__ tout,
                                                       float* __restrict__ xz) {
    __shared__ __align__(16) float ts[64 * 68];
    __shared__ float sc[64], sh[64];
    long m0 = (long)blockIdx.x << 6;
    int b = (int)(m0 >> 12);
    int hw0 = (int)(m0 & 4095);
    int tid = threadIdx.x;
    if (tid < 64) {
        float m = stats[tid] * (1.f / 16384.f);
        float var = stats[64 + tid] * (1.f / 16384.f) - m * m;
        float ss = g[tid] * rsqrtf(var + 1e-5f);
        sc[tid] = ss; sh[tid] = be[tid] - m * ss;
    }
    __syncthreads();
    for (int i = tid; i < 4096; i += 256) {
        int pix = i & 63, c = i >> 6;
        float v = src[(((long)((b << 6) + c)) << 12) + hw0 + pix];
        ts[pix * 68 + c] = fmaxf(v * sc[c] + sh[c], 0.f);
    }
    __syncthreads();
    for (int i = tid; i < 4096; i += 256) {
        int r = i >> 6, c = i & 63;
        tout[(m0 + r) * 64 + c] = ts[r * 68 + c];
    }
    int rg = tid >> 5;
    int cg = tid & 31;
    float acc[8][8] = {};
    int n0 = cg << 3;
    for (int k4 = 0; k4 < 16; ++k4) {
        float4 a[8];
        #pragma unroll
        for (int r2 = 0; r2 < 8; ++r2)
            a[r2] = *(const float4*)&ts[((rg << 3) + r2) * 68 + (k4 << 2)];
        #pragma unroll
        for (int kk = 0; kk < 4; ++kk) {
            const float* wr = wT + (((k4 << 2) + kk) << 8) + n0;
            float4 w0 = *(const float4*)&wr[0];
            float4 w1 = *(const float4*)&wr[4];
            #pragma unroll
            for (int r2 = 0; r2 < 8; ++r2) {
                float av = (kk == 0) ? a[r2].x : (kk == 1) ? a[r2].y
                         : (kk == 2) ? a[r2].z : a[r2].w;
                acc[r2][0] += av * w0.x; acc[r2][1] += av * w0.y;
                acc[r2][2] += av * w0.z; acc[r2][3] += av * w0.w;
                acc[r2][4] += av * w1.x; acc[r2][5] += av * w1.y;
                acc[r2][6] += av * w1.z; acc[r2][7] += av * w1.w;
            }
        }
    }
    #pragma unroll
    for (int r2 = 0; r2 < 8; ++r2) {
        long m = m0 + (rg << 3) + r2;
        *(float4*)&xz[(m << 8) + n0]     = make_float4(acc[r2][0], acc[r2][1], acc[r2][2], acc[r2][3]);
        *(float4*)&xz[(m << 8) + n0 + 4] = make_float4(acc[r2][4], acc[r2][5], acc[r2][6], acc[r2][7]);
    }
}

// ------- xproj (SUB=8): dwconv+SiLU + x_proj + delta + scan PHASE 1 -------
// 2048 blocks, ~11 KB LDS -> 8 blocks/CU (8 barrier groups; the only lever that
// moved R0->R5 was group count). Wx streamed from L1/L2 (18 KB, hot) instead of LDS.
__global__ __launch_bounds__(256, 4) void k_xproj_fused(
        const float* __restrict__ xz, const float* __restrict__ cw,
        const float* __restrict__ cb, const float* __restrict__ Wx,
        const float* __restrict__ dw, const float* __restrict__ dbias,
        const float* __restrict__ A_log,
        float* __restrict__ xi, float* __restrict__ delta,
        float* __restrict__ xdbc, float* __restrict__ Pb, float* __restrict__ Sb) {
    __shared__ __align__(16) float xz_s[WIN * 128];   // window; reused as delta_s
    __shared__ __align__(16) float xi_s[SUB * 128];
    __shared__ __align__(16) float xs[SUB * 36];
    long m0 = (long)blockIdx.x << 3;
    int l0 = (int)(m0 & 4095);
    int tid = threadIdx.x;

    // stage x-half window (3 halo rows + 8 own), vectorized
    for (int i = tid; i < WIN * 32; i += 256) {
        int j = i >> 5, c4 = (i & 31) << 2;
        float4 v = make_float4(0.f, 0.f, 0.f, 0.f);
        int l = l0 - 3 + j;
        if (l >= 0) v = *(const float4*)&xz[(m0 - 3 + j) * 256 + c4];
        *(float4*)&xz_s[j * 128 + c4] = v;
    }
    // per-thread dwconv weights (registers; channel group fixed)
    int d4c = (tid & 31) << 2;
    float4 cwv0 = *(const float4*)&cw[(d4c + 0) << 2];
    float4 cwv1 = *(const float4*)&cw[(d4c + 1) << 2];
    float4 cwv2 = *(const float4*)&cw[(d4c + 2) << 2];
    float4 cwv3 = *(const float4*)&cw[(d4c + 3) << 2];
    float4 cbv  = *(const float4*)&cb[d4c];
    __syncthreads();

    // dwconv + SiLU -> xi_s + global xi  (8 rows x 128 ch, one pass)
    {
        int r = tid >> 5;
        float4 x0 = *(const float4*)&xz_s[(r + 0) * 128 + d4c];
        float4 x1 = *(const float4*)&xz_s[(r + 1) * 128 + d4c];
        float4 x2 = *(const float4*)&xz_s[(r + 2) * 128 + d4c];
        float4 x3 = *(const float4*)&xz_s[(r + 3) * 128 + d4c];
        float4 a;
        a.x = cbv.x + x0.x * cwv0.x + x1.x * cwv0.y + x2.x * cwv0.z + x3.x * cwv0.w;
        a.y = cbv.y + x0.y * cwv1.x + x1.y * cwv1.y + x2.y * cwv1.z + x3.y * cwv1.w;
        a.z = cbv.z + x0.z * cwv2.x + x1.z * cwv2.y + x2.z * cwv2.z + x3.z * cwv2.w;
        a.w = cbv.w + x0.w * cwv3.x + x1.w * cwv3.y + x2.w * cwv3.z + x3.w * cwv3.w;
        a.x = a.x / (1.f + __expf(-a.x));
        a.y = a.y / (1.f + __expf(-a.y));
        a.z = a.z / (1.f + __expf(-a.z));
        a.w = a.w / (1.f + __expf(-a.w));
        *(float4*)&xi_s[r * 128 + d4c] = a;
        *(float4*)&xi[(m0 + r) * 128 + d4c] = a;
    }
    __syncthreads();

    // x_proj GEMM -> xs + xdbc; weights from global (L1-hot), 2-row reuse
    {
        int n = tid & 63, rg6 = tid >> 6;            // 4 row-groups x 2 rows = 8
        if (n < 36) {
            float acc[2] = {0, 0};
            for (int k4 = 0; k4 < 32; ++k4) {
                float4 w4 = *(const float4*)&Wx[(n << 7) + (k4 << 2)];
                #pragma unroll
                for (int r = 0; r < 2; ++r) {
                    float4 a4 = *(const float4*)&xi_s[((rg6 << 1) + r) * 128 + (k4 << 2)];
                    acc[r] += a4.x * w4.x + a4.y * w4.y + a4.z * w4.z + a4.w * w4.w;
                }
            }
            #pragma unroll
            for (int r = 0; r < 2; ++r) {
                int rr = (rg6 << 1) + r;
                xdbc[(m0 + rr) * 36 + n] = acc[r];
                xs[rr * 36 + n] = acc[r];
            }
        }
    }
    __syncthreads();

    // delta -> delta_s (reuse xz_s) + global delta
    float* delta_s = xz_s;
    for (int i = tid; i < SUB * 128; i += 256) {
        int r = i >> 7, di2 = i & 127;
        float4 d4 = *(const float4*)&dw[di2 << 2];
        float v = dbias[di2]
                + xs[r * 36 + 0] * d4.x + xs[r * 36 + 1] * d4.y
                + xs[r * 36 + 2] * d4.z + xs[r * 36 + 3] * d4.w;
        float sp = (v > 20.f) ? v : log1pf(expf(v));
        delta_s[r * 128 + di2] = sp;
        delta[(m0 + r) * 128 + di2] = sp;
    }
    __syncthreads();

    // scan PHASE 1: 8 steps, 8 states/thread; P/S at 8-row granularity
    {
        int di = tid >> 1;
        int dso = (tid & 1) << 3;
        float4 al0 = *(const float4*)&A_log[(di << 4) + dso];
        float4 al1 = *(const float4*)&A_log[(di << 4) + dso + 4];
        float Av[8] = { -expf(al0.x), -expf(al0.y), -expf(al0.z), -expf(al0.w),
                        -expf(al1.x), -expf(al1.y), -expf(al1.z), -expf(al1.w) };
        float h[8] = {0,0,0,0,0,0,0,0};
        float P[8] = {1,1,1,1,1,1,1,1};
        #pragma unroll
        for (int i = 0; i < SUB; ++i) {
            float d = delta_s[i * 128 + di];
            float u = xi_s[i * 128 + di];
            float du = d * u;
            float4 B0 = *(const float4*)&xs[i * 36 + DTRK + dso];
            float4 B1 = *(const float4*)&xs[i * 36 + DTRK + dso + 4];
            float a0 = __expf(d * Av[0]); h[0] = a0 * h[0] + du * B0.x; P[0] *= a0;
            float a1 = __expf(d * Av[1]); h[1] = a1 * h[1] + du * B0.y; P[1] *= a1;
            float a2 = __expf(d * Av[2]); h[2] = a2 * h[2] + du * B0.z; P[2] *= a2;
            float a3 = __expf(d * Av[3]); h[3] = a3 * h[3] + du * B0.w; P[3] *= a3;
            float a4 = __expf(d * Av[4]); h[4] = a4 * h[4] + du * B1.x; P[4] *= a4;
            float a5 = __expf(d * Av[5]); h[5] = a5 * h[5] + du * B1.y; P[5] *= a5;
            float a6 = __expf(d * Av[6]); h[6] = a6 * h[6] + du * B1.z; P[6] *= a6;
            float a7 = __expf(d * Av[7]); h[7] = a7 * h[7] + du * B1.w; P[7] *= a7;
        }
        long o = ((long)blockIdx.x << 11) + (di << 4) + dso;   // blockIdx == b*NSUB+sc
        *(float4*)&Pb[o]     = make_float4(P[0], P[1], P[2], P[3]);
        *(float4*)&Pb[o + 4] = make_float4(P[4], P[5], P[6], P[7]);
        *(float4*)&Sb[o]     = make_float4(h[0], h[1], h[2], h[3]);
        *(float4*)&Sb[o + 4] = make_float4(h[4], h[5], h[6], h[7]);
    }
}

// ---------------- scan phase 2: quad-combine + prefetch, 128 serial hops ----------------
// Reads 8-gran (P,S); writes per-sub-chunk h0 IN PLACE into Sb.
__global__ void k_scan_p2(const float* __restrict__ Pb, float* Sb) {
    int t = blockIdx.x * blockDim.x + threadIdx.x;
    int b = t >> 11;
    int s = t & 2047;
    long base = ((long)b * NSUB) << 11;
    float p[4], sv[4];
    #pragma unroll
    for (int k = 0; k < 4; ++k) {
        long idx = base + ((long)k << 11) + s;
        p[k] = Pb[idx]; sv[k] = Sb[idx];
    }
    float h = 0.f;
    for (int c = 0; c < 128; ++c) {
        float np[4] = {0, 0, 0, 0}, ns[4] = {0, 0, 0, 0};
        if (c < 127) {
            #pragma unroll
            for (int k = 0; k < 4; ++k) {
                long idx = base + ((long)(((c + 1) << 2) + k) << 11) + s;
                np[k] = Pb[idx]; ns[k] = Sb[idx];
            }
        }
        long i0 = base + ((long)(c << 2) << 11) + s;
        Sb[i0]        = h;  h = p[0] * h + sv[0];
        Sb[i0 + 2048] = h;  h = p[1] * h + sv[1];
        Sb[i0 + 4096] = h;  h = p[2] * h + sv[2];
        Sb[i0 + 6144] = h;  h = p[3] * h + sv[3];
        #pragma unroll
        for (int k = 0; k < 4; ++k) { p[k] = np[k]; sv[k] = ns[k]; }
    }
}

// ------- scan phase 3 (SUB=8): stage + scan(+fused gating) + out_proj
//         + residual + next-layer in_proj (in place; own rows only) -------
// ~16 KB LDS -> 8 blocks/CU. Gating fused into scan (z staged up front) saves a
// phase + barrier + LDS pass. (256,4): cap 128, natural demand ~52 -> 8 waves/SIMD.
__global__ __launch_bounds__(256, 4) void k_scan_p3_oi(
        float* xz, const float* __restrict__ xi, const float* __restrict__ delta,
        const float* __restrict__ xdbc,
        const float* __restrict__ A_log, const float* __restrict__ Dp,
        const float* __restrict__ wTo, const float* __restrict__ wTi,
        float* __restrict__ tio, const float* __restrict__ h0g, int doB) {
    __shared__ __align__(16) float d_s[SUB * 128];
    __shared__ __align__(16) float u_s[SUB * 132];    // xi -> gated y
    __shared__ __align__(16) float z_s[SUB * 132];
    __shared__ __align__(16) float bc_s[SUB * 36];    // dt|B|C
    __shared__ __align__(16) float t_s[SUB * 68];
    long m0 = (long)blockIdx.x << 3;
    int tid = threadIdx.x;

    // stage delta + xi + z (one float4 per thread per array)
    {
        int r = tid >> 5, c4 = (tid & 31) << 2;
        *(float4*)&d_s[r * 128 + c4] = *(const float4*)&delta[(m0 + r) * 128 + c4];
        *(float4*)&u_s[r * 132 + c4] = *(const float4*)&xi[(m0 + r) * 128 + c4];
        *(float4*)&z_s[r * 132 + c4] = *(const float4*)&xz[((m0 + r) << 8) + DIM + c4];
    }
    // stage dt|B|C
    if (tid < SUB * 9) {
        int r = tid / 9, c4 = (tid - r * 9) << 2;
        *(float4*)&bc_s[r * 36 + c4] = *(const float4*)&xdbc[(m0 + r) * 36 + c4];
    }
    // per-thread scan state
    int di = tid >> 1;
    int dso = (tid & 1) << 3;
    float4 al0 = *(const float4*)&A_log[(di << 4) + dso];
    float4 al1 = *(const float4*)&A_log[(di << 4) + dso + 4];
    float Av[8] = { -expf(al0.x), -expf(al0.y), -expf(al0.z), -expf(al0.w),
                    -expf(al1.x), -expf(al1.y), -expf(al1.z), -expf(al1.w) };
    float Dv = Dp[di];
    long o = ((long)blockIdx.x << 11) + (di << 4) + dso;
    float4 h04 = *(const float4*)&h0g[o];
    float4 h14 = *(const float4*)&h0g[o + 4];
    float h[8] = { h04.x, h04.y, h04.z, h04.w, h14.x, h14.y, h14.z, h14.w };
    __syncthreads();

    // 8-step scan with FUSED gating (lane pair owns di; overwrites u with gated y)
    #pragma unroll
    for (int i = 0; i < SUB; ++i) {
        float d = d_s[i * 128 + di];
        float u = u_s[i * 132 + di];
        float du = d * u;
        const float* bc = &bc_s[i * 36];
        float4 B0 = *(const float4*)&bc[DTRK + dso];
        float4 B1 = *(const float4*)&bc[DTRK + dso + 4];
        float4 C0 = *(const float4*)&bc[DTRK + DSN + dso];
        float4 C1 = *(const float4*)&bc[DTRK + DSN + dso + 4];
        float a0 = __expf(d * Av[0]); h[0] = a0 * h[0] + du * B0.x;
        float a1 = __expf(d * Av[1]); h[1] = a1 * h[1] + du * B0.y;
        float a2 = __expf(d * Av[2]); h[2] = a2 * h[2] + du * B0.z;
        float a3 = __expf(d * Av[3]); h[3] = a3 * h[3] + du * B0.w;
        float a4 = __expf(d * Av[4]); h[4] = a4 * h[4] + du * B1.x;
        float a5 = __expf(d * Av[5]); h[5] = a5 * h[5] + du * B1.y;
        float a6 = __expf(d * Av[6]); h[6] = a6 * h[6] + du * B1.z;
        float a7 = __expf(d * Av[7]); h[7] = a7 * h[7] + du * B1.w;
        float yp = h[0] * C0.x + h[1] * C0.y + h[2] * C0.z + h[3] * C0.w
                 + h[4] * C1.x + h[5] * C1.y + h[6] * C1.z + h[7] * C1.w;
        yp += __shfl_xor(yp, 1);
        if (dso == 0) {
            float z = z_s[i * 132 + di];
            u_s[i * 132 + di] = (yp + u * Dv) * (z / (1.f + __expf(-z)));
        }
    }
    __syncthreads();

    // out_proj + residual: 8x64, K=128. thread = (1 row, 2 cols), all 256 active
    {
        int rg = tid >> 5, cg = tid & 31;
        int n0 = cg << 1;
        float acc2[2] = {0.f, 0.f};
        for (int k4 = 0; k4 < 32; ++k4) {
            float4 a0 = *(const float4*)&u_s[rg * 132 + (k4 << 2)];
            #pragma unroll
            for (int kk = 0; kk < 4; ++kk) {
                const float* wr = wTo + (((k4 << 2) + kk) << 6) + n0;
                float2 w0 = *(const float2*)&wr[0];
                float av = (kk == 0) ? a0.x : (kk == 1) ? a0.y : (kk == 2) ? a0.z : a0.w;
                acc2[0] += av * w0.x; acc2[1] += av * w0.y;
            }
        }
        long m = m0 + rg;
        float2 tv = *(const float2*)&tio[(m << 6) + n0];
        tv.x += acc2[0]; tv.y += acc2[1];
        *(float2*)&tio[(m << 6) + n0] = tv;
        *(float2*)&t_s[rg * 68 + n0] = tv;
    }
    if (!doB) return;
    __syncthreads();

    // in_proj (next layer): 8x256, K=64. thread = (1 row, 8 cols); in-place xz
    {
        int rg = tid >> 5, cgn = tid & 31;
        int n0 = cgn << 3;
        float acc[8] = {};
        for (int k4 = 0; k4 < 16; ++k4) {
            float4 a0 = *(const float4*)&t_s[rg * 68 + (k4 << 2)];
            #pragma unroll
            for (int kk = 0; kk < 4; ++kk) {
                const float* wr = wTi + (((k4 << 2) + kk) << 8) + n0;
                float4 w0 = *(const float4*)&wr[0];
                float4 w1 = *(const float4*)&wr[4];
                float av = (kk == 0) ? a0.x : (kk == 1) ? a0.y : (kk == 2) ? a0.z : a0.w;
                acc[0] += av * w0.x; acc[1] += av * w0.y;
                acc[2] += av * w0.z; acc[3] += av * w0.w;
                acc[4] += av * w1.x; acc[5] += av * w1.y;
                acc[6] += av * w1.z; acc[7] += av * w1.w;
            }
        }
        long m = m0 + rg;
        *(float4*)&xz[(m << 8) + n0]     = make_float4(acc[0], acc[1], acc[2], acc[3]);
        *(float4*)&xz[(m << 8) + n0 + 4] = make_float4(acc[4], acc[5], acc[6], acc[7]);
    }
}

// ---------------- decoder conv1 + fused BN-stat partials ----------------
__global__ __launch_bounds__(256, 1) void k_dec1_new(const float* __restrict__ tin,
                                                     const float* __restrict__ wT,
                                                     const float* __restrict__ bias,
                                                     float* __restrict__ out,
                                                     float* __restrict__ stats2) {
    __shared__ __align__(16) float x_s[64 * 132];
    __shared__ __align__(16) float w_s[4 * 4608];
    int tile = blockIdx.x;
    int b = blockIdx.y;
    int ty0 = (tile >> 3) << 3;
    int tx0 = (tile & 7) << 3;
    int tid = threadIdx.x;
    int wv = tid >> 6;
    int lane = tid & 63;
    int r = lane >> 3;
    int cg = lane & 7;

    for (int i = tid; i < 6400; i += 256) {
        int pl = i >> 6;
        int c = i & 63;
        int py = pl / 10, px = pl - py * 10;
        int ih = ty0 + py - 1, iw = tx0 + px - 1;
        float v = 0.f;
        if (ih >= 0 && ih < HH && iw >= 0 && iw < WWD)
            v = tin[(((long)((b << 12) + (ih << 6) + iw)) << 6) + c];
        x_s[c * 132 + py * 12 + px] = v;
    }
    float* myw = &w_s[wv * 4608];
    const float* gw = wT + (wv * 16) * 576;
    float4 pref[18];
    #pragma unroll
    for (int i = 0; i < 18; ++i)
        pref[i] = *(const float4*)&gw[(i * 64 + lane) * 4];
    #pragma unroll
    for (int i = 0; i < 18; ++i)
        *(float4*)&myw[(i * 64 + lane) * 4] = pref[i];
    __syncthreads();

    float acc[8][8] = {};
    #pragma unroll
    for (int ch = 0; ch < 2; ++ch) {
        if (ch == 0) {
            const float* gw1 = wT + (wv * 16 + 8) * 576;
            #pragma unroll
            for (int i = 0; i < 18; ++i)
                pref[i] = *(const float4*)&gw1[(i * 64 + lane) * 4];
        }
        for (int cl = 0; cl < 8; ++cl) {
            int cib = wv * 16 + ch * 8 + cl;
            float xrow[3][10];
            #pragma unroll
            for (int kh = 0; kh < 3; ++kh) {
                const float* xr = &x_s[cib * 132 + (r + kh) * 12];
                float4 a0 = *(const float4*)&xr[0];
                float4 a1 = *(const float4*)&xr[4];
                float2 a2 = *(const float2*)&xr[8];
                xrow[kh][0] = a0.x; xrow[kh][1] = a0.y; xrow[kh][2] = a0.z; xrow[kh][3] = a0.w;
                xrow[kh][4] = a1.x; xrow[kh][5] = a1.y; xrow[kh][6] = a1.z; xrow[kh][7] = a1.w;
                xrow[kh][8] = a2.x; xrow[kh][9] = a2.y;
            }
            const float* wp = &myw[cl * 576];
            #pragma unroll
            for (int kh = 0; kh < 3; ++kh) {
                #pragma unroll
                for (int kw = 0; kw < 3; ++kw) {
                    const float* wp2 = wp + (kh * 3 + kw) * 64 + (cg << 3);
                    float4 wa = *(const float4*)&wp2[0];
                    float4 wb = *(const float4*)&wp2[4];
                    #pragma unroll
                    for (int j = 0; j < 8; ++j) {
                        float xv = xrow[kh][kw + j];
                        acc[j][0] += xv * wa.x; acc[j][1] += xv * wa.y;
                        acc[j][2] += xv * wa.z; acc[j][3] += xv * wa.w;
                        acc[j][4] += xv * wb.x; acc[j][5] += xv * wb.y;
                        acc[j][6] += xv * wb.z; acc[j][7] += xv * wb.w;
                    }
                }
            }
        }
        if (ch == 0) {
            #pragma unroll
            for (int i = 0; i < 18; ++i)
                *(float4*)&myw[(i * 64 + lane) * 4] = pref[i];
        }
    }

    #pragma unroll
    for (int j = 0; j < 8; ++j) {
        *(float4*)&myw[lane * 68 + (j << 3)]     = make_float4(acc[j][0], acc[j][1], acc[j][2], acc[j][3]);
        *(float4*)&myw[lane * 68 + (j << 3) + 4] = make_float4(acc[j][4], acc[j][5], acc[j][6], acc[j][7]);
    }
    __syncthreads();

    float bv = bias[lane];
    float ssum = 0.f, ssq = 0.f;
    #pragma unroll
    for (int pp = 0; pp < 16; ++pp) {
        int pr = (wv << 1) + (pp >> 3);
        int pc = pp & 7;
        int ol = (pr << 3) + (lane >> 3);
        int ix = (pc << 3) + (lane & 7);
        float s = w_s[ol * 68 + ix] + w_s[4608 + ol * 68 + ix]
                + w_s[9216 + ol * 68 + ix] + w_s[13824 + ol * 68 + ix] + bv;
        out[(((long)((b << 12) + ((ty0 + pr) << 6) + tx0 + pc)) << 6) + lane] = s;
        ssum += s; ssq += s * s;
    }
    float* red = x_s;
    red[(wv << 6) + lane] = ssum;
    red[256 + (wv << 6) + lane] = ssq;
    __syncthreads();
    if (tid < 64) {
        float a = red[tid] + red[64 + tid] + red[128 + tid] + red[192 + tid];
        float q = red[256 + tid] + red[320 + tid] + red[384 + tid] + red[448 + tid];
        atomicAdd(&stats2[tid], a);
        atomicAdd(&stats2[64 + tid], q);
    }
}

// ------- decoder conv2 FUSED with BN+ReLU (inline stats) -------
__global__ void k_dec2_fused(const float* __restrict__ src, const float* __restrict__ stats2,
                             const float* __restrict__ g, const float* __restrict__ be,
                             const float* __restrict__ wT, const float* __restrict__ bias,
                             float* __restrict__ out) {
    __shared__ float x_s[64 * 101];
    __shared__ float w_s[64 * NFC * 12];
    __shared__ float sc_s[64];
    __shared__ float sh_s[64];
    int tile = blockIdx.x;
    int b = blockIdx.y;
    int ty0 = (tile >> 3) << 3;
    int tx0 = (tile & 7) << 3;
    int tid = threadIdx.x;

    if (tid < 64) {
        float m = stats2[tid] * (1.f / 16384.f);
        float var = stats2[64 + tid] * (1.f / 16384.f) - m * m;
        float s = g[tid] * rsqrtf(var + 1e-5f);
        sc_s[tid] = s;
        sh_s[tid] = be[tid] - m * s;
    }
    for (int i = tid; i < 64 * NFC * 12; i += 256)
        w_s[i] = wT[i];
    __syncthreads();

    for (int i = tid; i < 6400; i += 256) {
        int pl = i >> 6;
        int c = i & 63;
        int py = pl / 10, px = pl - py * 10;
        int ih = ty0 + py - 1, iw = tx0 + px - 1;
        float v = 0.f;
        if (ih >= 0 && ih < HH && iw >= 0 && iw < WWD) {
            v = src[((long)((b << 12) + (ih << 6) + iw)) * 64 + c];
            v = fmaxf(v * sc_s[c] + sh_s[c], 0.f);
        }
        x_s[c * 101 + pl] = v;
    }
    __syncthreads();

    int px = tid & 63;
    int py = px >> 3, pxx = px & 7;
    int cog = tid >> 6;
    float acc[3] = {0.f, 0.f, 0.f};
    int nco = (cog < 2) ? 3 : 2;

    for (int ci = 0; ci < 64; ++ci) {
        const float* xr = &x_s[ci * 101 + py * 10 + pxx];
        float xv[9];
        #pragma unroll
        for (int kh = 0; kh < 3; ++kh)
            #pragma unroll
            for (int kw = 0; kw < 3; ++kw)
                xv[kh * 3 + kw] = xr[kh * 10 + kw];
        #pragma unroll
        for (int j = 0; j < 3; ++j) {
            if (j >= nco) break;
            int co = cog + (j << 2);
            const float* wp = &w_s[(ci * NFC + co) * 12];
            float4 w0 = *(const float4*)&wp[0];
            float4 w1 = *(const float4*)&wp[4];
            float  w8 = wp[8];
            acc[j] += xv[0] * w0.x + xv[1] * w0.y + xv[2] * w0.z + xv[3] * w0.w
                    + xv[4] * w1.x + xv[5] * w1.y + xv[6] * w1.z + xv[7] * w1.w
                    + xv[8] * w8;
        }
    }
    int hw = ((ty0 + py) << 6) + tx0 + pxx;
    #pragma unroll
    for (int j = 0; j < 3; ++j) {
        if (j >= nco) break;
        int co = cog + (j << 2);
        out[((long)(b * NFC + co) << 12) + hw] = acc[j] + bias[co];
    }
}

extern "C" void kernel_launch(void* const* d_in, const int* in_sizes, int n_in,
                              void* d_out, int out_size, void* d_ws, size_t ws_size,
                              hipStream_t stream) {
    const float* x       = (const float*)d_in[0];
    const float* enc_w   = (const float*)d_in[1];
    const float* enc_b   = (const float*)d_in[2];
    const float* enc_g   = (const float*)d_in[3];
    const float* enc_be  = (const float*)d_in[4];
    const float* in_proj = (const float*)d_in[5];
    const float* conv_w  = (const float*)d_in[6];
    const float* conv_b  = (const float*)d_in[7];
    const float* x_proj  = (const float*)d_in[8];
    const float* dt_w    = (const float*)d_in[9];
    const float* dt_b    = (const float*)d_in[10];
    const float* A_log   = (const float*)d_in[11];
    const float* Dp      = (const float*)d_in[12];
    const float* out_prj = (const float*)d_in[13];
    const float* dec1_w  = (const float*)d_in[14];
    const float* dec1_b  = (const float*)d_in[15];
    const float* dec1_g  = (const float*)d_in[16];
    const float* dec1_be = (const float*)d_in[17];
    const float* dec2_w  = (const float*)d_in[18];
    const float* dec2_b  = (const float*)d_in[19];
    float* out = (float*)d_out;

    float* ws = (float*)d_ws;
    size_t off = 0;
    float* conv_buf  = ws + off; off += 1048576;  // enc out / dec scratch
    float* stats     = ws + off; off += 128;
    float* stats2    = ws + off; off += 128;
    float* wT1       = ws + off; off += 36864;
    float* wT2       = ws + off; off += 7680;
    float* wTin      = ws + off; off += 65536;
    float* wTout     = ws + off; off += 32768;
    float* t_buf     = ws + off; off += 1048576;
    float* xz_buf    = ws + off; off += 4194304;
    float* xi_buf    = ws + off; off += 2097152;
    float* delta_buf = ws + off; off += 2097152;
    float* xdbc_buf  = ws + off; off += 589824;
    float* Pb        = ws + off; off += 4194304;  // 8-gran aggregates
    float* Sb        = ws + off; off += 4194304;  // 8-gran; becomes h0 after p2
    (void)ws_size; (void)in_sizes; (void)n_in; (void)out_size;

    // prep: transposes + zero stats (runs every launch; graph-safe)
    k_prep_all<<<560, 256, 0, stream>>>(in_proj, out_prj, dec1_w, dec2_w,
                                        wTin, wTout, wT1, wT2, stats, stats2);

    // encoder (BN-apply fused into first in_proj)
    k_enc_conv<<<4096, 256, 0, stream>>>(x, enc_w, enc_b, conv_buf, stats);

    // first in_proj
    k_gemm_in_bn<<<256, 256, 0, stream>>>(conv_buf, stats, enc_g, enc_be, wTin,
                                          t_buf, xz_buf);

    // mamba layers (SUB=8 -> 2048 blocks = 8 blocks/CU per kernel)
    for (int i = 0; i < NLAYER; ++i) {
        int doB = (i < NLAYER - 1) ? 1 : 0;
        k_xproj_fused<<<2048, 256, 0, stream>>>(
            xz_buf, conv_w + i * DIM * DCN, conv_b + i * DIM, x_proj + i * 36 * DIM,
            dt_w + i * DIM * DTRK, dt_b + i * DIM, A_log + i * DIM * DSN,
            xi_buf, delta_buf, xdbc_buf, Pb, Sb);
        k_scan_p2<<<32, 256, 0, stream>>>(Pb, Sb);
        k_scan_p3_oi<<<2048, 256, 0, stream>>>(
            xz_buf, xi_buf, delta_buf, xdbc_buf,
            A_log + i * DIM * DSN, Dp + i * DIM,
            wTout + i * 8192, wTin + ((i + 1) & 3) * 16384,
            t_buf, Sb, doB);
    }

    // decoder
    dim3 dg1(64, BB);
    k_dec1_new<<<dg1, 256, 0, stream>>>(t_buf, wT1, dec1_b, conv_buf, stats2);
    k_dec2_fused<<<dg1, 256, 0, stream>>>(conv_buf, stats2, dec1_g, dec1_be, wT2, dec2_b, out);
}

// Round 7
// 502.351 us; speedup vs baseline: 1.4812x; 1.4812x over previous
//
#include <hip/hip_runtime.h>
#include <hip/hip_bf16.h>

// Problem constants (MinimalEventMamba)
#define BB   4
#define NBC  5
#define HD   64
#define NLAYER 4
#define NFC  10
#define DIM  128
#define DSN  16
#define DCN  4
#define DTRK 4
#define HH   64
#define WWD  64
#define LL   4096
#define MM   (BB*LL)
#define CLEN   32          // chunk length (rows per block), 512 blocks
#define NCHUNK 128         // chunks per batch

// constant-folded component access for fully-unrolled loops (rule: no runtime
// indexing of register arrays -> scratch)
#define A4GET(a, i) (((i) & 3) == 0 ? (a)[(i) >> 2].x : ((i) & 3) == 1 ? (a)[(i) >> 2].y : \
                     ((i) & 3) == 2 ? (a)[(i) >> 2].z : (a)[(i) >> 2].w)

// ---------------- prep: all weight transposes + zero stats ----------------
__global__ void k_prep_all(const float* __restrict__ in_proj, const float* __restrict__ out_proj,
                           const float* __restrict__ dec1_w, const float* __restrict__ dec2_w,
                           float* __restrict__ wTin, float* __restrict__ wTout,
                           float* __restrict__ wT1, float* __restrict__ wT2,
                           float* __restrict__ stats, float* __restrict__ stats2) {
    int idx = blockIdx.x * blockDim.x + threadIdx.x;
    if (idx < 65536) {
        int n = idx & 255, k = (idx >> 8) & 63, l = idx >> 14;
        wTin[idx] = in_proj[(l << 14) + (n << 6) + k];
    } else if (idx < 98304) {
        int j = idx - 65536;
        int n = j & 63, k = (j >> 6) & 127, l = j >> 13;
        wTout[j] = out_proj[(l << 13) + (n << 7) + k];
    } else if (idx < 135168) {
        int j = idx - 98304;
        int co = j & 63, tap = (j >> 6) % 9, ci = j / 576;
        wT1[j] = dec1_w[co * 576 + ci * 9 + tap];
    } else if (idx < 142848) {
        int j = idx - 135168;
        int tap = j % 12, t2 = j / 12, co = t2 % NFC, ci = t2 / NFC;
        wT2[j] = (tap < 9) ? dec2_w[co * 576 + ci * 9 + tap] : 0.f;
    } else if (idx < 143104) {
        int j = idx - 142848;
        if (j < 128) stats[j] = 0.f; else stats2[j - 128] = 0.f;
    }
}

// ---------------- Encoder conv + fused BN-stat partials ----------------
__global__ void k_enc_conv(const float* __restrict__ x, const float* __restrict__ w,
                           const float* __restrict__ bias, float* __restrict__ out,
                           float* __restrict__ stats) {
    __shared__ float r1[256], r2[256];
    int tid = threadIdx.x;
    int idx = blockIdx.x * 256 + tid;
    int wx = idx & 63;
    int hy = (idx >> 6) & 63;
    int co = (idx >> 12) & 63;
    int b  = idx >> 18;
    float acc = bias[co];
    for (int ci = 0; ci < NBC; ++ci) {
        const float* xin = x + (((long)(b * NBC + ci)) << 12);
        const float* wp  = w + (co * NBC + ci) * 9;
        #pragma unroll
        for (int kh = 0; kh < 3; ++kh) {
            int ih = hy + kh - 1;
            if (ih < 0 || ih >= HH) continue;
            #pragma unroll
            for (int kw = 0; kw < 3; ++kw) {
                int iw = wx + kw - 1;
                if (iw < 0 || iw >= WWD) continue;
                acc += xin[(ih << 6) + iw] * wp[kh * 3 + kw];
            }
        }
    }
    out[idx] = acc;
    r1[tid] = acc; r2[tid] = acc * acc;
    __syncthreads();
    for (int off = 128; off > 0; off >>= 1) {
        if (tid < off) { r1[tid] += r1[tid + off]; r2[tid] += r2[tid + off]; }
        __syncthreads();
    }
    if (tid == 0) {
        atomicAdd(&stats[co], r1[0]);
        atomicAdd(&stats[64 + co], r2[0]);
    }
}

// ---- in_proj GEMM (first layer) with FUSED BN+ReLU apply ----
__global__ __launch_bounds__(256, 1) void k_gemm_in_bn(const float* __restrict__ src,
                                                       const float* __restrict__ stats,
                                                       const float* __restrict__ g,
                                                       const float* __restrict__ be,
                                                       const float* __restrict__ wT,
                                                       float* __restrict__ tout,
                                                       float* __restrict__ xz) {
    __shared__ __align__(16) float ts[64 * 68];
    __shared__ float sc[64], sh[64];
    long m0 = (long)blockIdx.x << 6;
    int b = (int)(m0 >> 12);
    int hw0 = (int)(m0 & 4095);
    int tid = threadIdx.x;
    if (tid < 64) {
        float m = stats[tid] * (1.f / 16384.f);
        float var = stats[64 + tid] * (1.f / 16384.f) - m * m;
        float ss = g[tid] * rsqrtf(var + 1e-5f);
        sc[tid] = ss; sh[tid] = be[tid] - m * ss;
    }
    __syncthreads();
    for (int i = tid; i < 4096; i += 256) {
        int pix = i & 63, c = i >> 6;
        float v = src[(((long)((b << 6) + c)) << 12) + hw0 + pix];
        ts[pix * 68 + c] = fmaxf(v * sc[c] + sh[c], 0.f);
    }
    __syncthreads();
    for (int i = tid; i < 4096; i += 256) {
        int r = i >> 6, c = i & 63;
        tout[(m0 + r) * 64 + c] = ts[r * 68 + c];
    }
    int rg = tid >> 5;
    int cg = tid & 31;
    float acc[8][8] = {};
    int n0 = cg << 3;
    for (int k4 = 0; k4 < 16; ++k4) {
        float4 a[8];
        #pragma unroll
        for (int r2 = 0; r2 < 8; ++r2)
            a[r2] = *(const float4*)&ts[((rg << 3) + r2) * 68 + (k4 << 2)];
        #pragma unroll
        for (int kk = 0; kk < 4; ++kk) {
            const float* wr = wT + (((k4 << 2) + kk) << 8) + n0;
            float4 w0 = *(const float4*)&wr[0];
            float4 w1 = *(const float4*)&wr[4];
            #pragma unroll
            for (int r2 = 0; r2 < 8; ++r2) {
                float av = (kk == 0) ? a[r2].x : (kk == 1) ? a[r2].y
                         : (kk == 2) ? a[r2].z : a[r2].w;
                acc[r2][0] += av * w0.x; acc[r2][1] += av * w0.y;
                acc[r2][2] += av * w0.z; acc[r2][3] += av * w0.w;
                acc[r2][4] += av * w1.x; acc[r2][5] += av * w1.y;
                acc[r2][6] += av * w1.z; acc[r2][7] += av * w1.w;
            }
        }
    }
    #pragma unroll
    for (int r2 = 0; r2 < 8; ++r2) {
        long m = m0 + (rg << 3) + r2;
        *(float4*)&xz[(m << 8) + n0]     = make_float4(acc[r2][0], acc[r2][1], acc[r2][2], acc[r2][3]);
        *(float4*)&xz[(m << 8) + n0 + 4] = make_float4(acc[r2][4], acc[r2][5], acc[r2][6], acc[r2][7]);
    }
}

// ------- xproj (CLEN=32): dwconv+SiLU + x_proj + delta + scan PHASE 1 -------
// Writes delta/xi TRANSPOSED ([di][m]) so p3 can register-stage its own column.
__global__ __launch_bounds__(512, 4) void k_xproj_fused(
        const float* __restrict__ xz, const float* __restrict__ cw,
        const float* __restrict__ cb, const float* __restrict__ Wx,
        const float* __restrict__ dw, const float* __restrict__ dbias,
        const float* __restrict__ A_log,
        float* __restrict__ xiT, float* __restrict__ deltaT,
        float* __restrict__ xdbc, float* __restrict__ Pb, float* __restrict__ Sb) {
    __shared__ __align__(16) float xz_s[35 * 132];     // window; reused as delta_s
    __shared__ __align__(16) float xi_s[32 * 132];
    __shared__ __align__(16) float w_s[36 * 132];
    __shared__ __align__(16) float xs[32 * 40];
    __shared__ float cwT[4 * 128];
    __shared__ float cb_s[128];
    long m0 = (long)blockIdx.x << 5;
    int l0 = (int)(m0 & 4095);
    int tid = threadIdx.x;

    // stage x-half window (3 halo rows + 32 own), vectorized
    for (int i = tid; i < 35 * 32; i += 512) {
        int j = i >> 5, c4 = (i & 31) << 2;
        float4 v = make_float4(0.f, 0.f, 0.f, 0.f);
        if (l0 - 3 + j >= 0) v = *(const float4*)&xz[(m0 - 3 + j) * 256 + c4];
        *(float4*)&xz_s[j * 132 + c4] = v;
    }
    if (tid < 128) cb_s[tid] = cb[tid];
    { int kk = tid >> 7, dii = tid & 127; if (tid < 512) cwT[(kk << 7) + dii] = cw[(dii << 2) + kk]; }
    for (int i = tid; i < 1152; i += 512) {
        int n = i >> 5, c4 = (i & 31) << 2;
        *(float4*)&w_s[n * 132 + c4] = *(const float4*)&Wx[(n << 7) + c4];
    }
    __syncthreads();

    // dwconv + SiLU -> xi_s (LDS only; transposed global write happens later)
    #pragma unroll
    for (int ii = 0; ii < 2; ++ii) {
        int i = tid + (ii << 9);
        int r = i >> 5, d4 = (i & 31) << 2;
        float4 a = *(const float4*)&cb_s[d4];
        #pragma unroll
        for (int kk = 0; kk < 4; ++kk) {
            float4 xv = *(const float4*)&xz_s[(r + kk) * 132 + d4];
            float4 wv = *(const float4*)&cwT[(kk << 7) + d4];
            a.x += xv.x * wv.x; a.y += xv.y * wv.y;
            a.z += xv.z * wv.z; a.w += xv.w * wv.w;
        }
        a.x = a.x / (1.f + __expf(-a.x));
        a.y = a.y / (1.f + __expf(-a.y));
        a.z = a.z / (1.f + __expf(-a.z));
        a.w = a.w / (1.f + __expf(-a.w));
        *(float4*)&xi_s[r * 132 + d4] = a;
    }
    __syncthreads();

    // x_proj GEMM -> xs + xdbc
    {
        int n = tid & 63, rg6 = tid >> 6;
        if (n < 36) {
            float acc[4] = {0, 0, 0, 0};
            for (int k4 = 0; k4 < 32; ++k4) {
                float4 w4 = *(const float4*)&w_s[n * 132 + (k4 << 2)];
                #pragma unroll
                for (int r = 0; r < 4; ++r) {
                    float4 a4 = *(const float4*)&xi_s[((rg6 << 2) + r) * 132 + (k4 << 2)];
                    acc[r] += a4.x * w4.x + a4.y * w4.y + a4.z * w4.z + a4.w * w4.w;
                }
            }
            #pragma unroll
            for (int r = 0; r < 4; ++r) {
                int rr = (rg6 << 2) + r;
                xdbc[(m0 + rr) * 36 + n] = acc[r];
                xs[rr * 40 + n] = acc[r];
            }
        }
    }
    __syncthreads();

    // delta -> delta_s (reuse xz_s)
    float* delta_s = xz_s;
    for (int i = tid; i < 4096; i += 512) {
        int r = i >> 7, di2 = i & 127;
        float4 d4 = *(const float4*)&dw[di2 << 2];
        float v = dbias[di2]
                + xs[r * 40 + 0] * d4.x + xs[r * 40 + 1] * d4.y
                + xs[r * 40 + 2] * d4.z + xs[r * 40 + 3] * d4.w;
        float sp = (v > 20.f) ? v : log1pf(expf(v));
        delta_s[r * 132 + di2] = sp;
    }
    __syncthreads();

    // transposed write-out (read-only on delta_s/xi_s; overlaps with p1 scan below)
    {
        int dii = tid & 127, q = tid >> 7;          // 128 di x 4 row-quarters
        float td[8], tu[8];
        #pragma unroll
        for (int j = 0; j < 8; ++j) {
            td[j] = delta_s[((q << 3) + j) * 132 + dii];
            tu[j] = xi_s[((q << 3) + j) * 132 + dii];
        }
        long tb = (long)dii * MM + m0 + (q << 3);
        *(float4*)&deltaT[tb]     = make_float4(td[0], td[1], td[2], td[3]);
        *(float4*)&deltaT[tb + 4] = make_float4(td[4], td[5], td[6], td[7]);
        *(float4*)&xiT[tb]        = make_float4(tu[0], tu[1], tu[2], tu[3]);
        *(float4*)&xiT[tb + 4]    = make_float4(tu[4], tu[5], tu[6], tu[7]);
    }

    // scan PHASE 1: 32 steps, 4 states/thread
    {
        int di = tid >> 2;
        int dso = (tid & 3) << 2;
        float4 al = *(const float4*)&A_log[(di << 4) + dso];
        float Av[4] = { -expf(al.x), -expf(al.y), -expf(al.z), -expf(al.w) };
        float h[4] = {0, 0, 0, 0};
        float P[4] = {1, 1, 1, 1};
        #pragma unroll 4
        for (int i = 0; i < CLEN; ++i) {
            float d = delta_s[i * 132 + di];
            float u = xi_s[i * 132 + di];
            float du = d * u;
            float4 B0 = *(const float4*)&xs[i * 40 + DTRK + dso];
            float a0 = __expf(d * Av[0]); h[0] = a0 * h[0] + du * B0.x; P[0] *= a0;
            float a1 = __expf(d * Av[1]); h[1] = a1 * h[1] + du * B0.y; P[1] *= a1;
            float a2 = __expf(d * Av[2]); h[2] = a2 * h[2] + du * B0.z; P[2] *= a2;
            float a3 = __expf(d * Av[3]); h[3] = a3 * h[3] + du * B0.w; P[3] *= a3;
        }
        long o = ((long)blockIdx.x << 11) + (di << 4) + dso;
        *(float4*)&Pb[o] = make_float4(P[0], P[1], P[2], P[3]);
        *(float4*)&Sb[o] = make_float4(h[0], h[1], h[2], h[3]);
    }
}

// ---------------- scan phase 2: quad-combine + prefetch, 32 serial hops ----------------
// Reads 32-gran (P,S); writes per-chunk h0 IN PLACE into Sb.
__global__ void k_scan_p2(const float* __restrict__ Pb, float* Sb) {
    int t = blockIdx.x * blockDim.x + threadIdx.x;     // 8192 threads
    int b = t >> 11;
    int s = t & 2047;
    long base = (long)b << 18;                          // b * 128 * 2048
    float p[4], sv[4];
    #pragma unroll
    for (int k = 0; k < 4; ++k) {
        long idx = base + ((long)k << 11) + s;
        p[k] = Pb[idx]; sv[k] = Sb[idx];
    }
    float h = 0.f;
    for (int c = 0; c < 32; ++c) {
        float np[4] = {0, 0, 0, 0}, ns[4] = {0, 0, 0, 0};
        if (c < 31) {
            #pragma unroll
            for (int k = 0; k < 4; ++k) {
                long idx = base + ((long)(((c + 1) << 2) + k) << 11) + s;
                np[k] = Pb[idx]; ns[k] = Sb[idx];
            }
        }
        long i0 = base + ((long)(c << 2) << 11) + s;
        Sb[i0]        = h;  h = p[0] * h + sv[0];
        Sb[i0 + 2048] = h;  h = p[1] * h + sv[1];
        Sb[i0 + 4096] = h;  h = p[2] * h + sv[2];
        Sb[i0 + 6144] = h;  h = p[3] * h + sv[3];
        #pragma unroll
        for (int k = 0; k < 4; ++k) { p[k] = np[k]; sv[k] = ns[k]; }
    }
}

// ------- scan phase 3 (CLEN=32): REGISTER-STAGED scan (+fused gating)
//         + out_proj + residual + next-layer in_proj (in place; own rows only) -------
// delta/xi read column-major direct to registers (even lane: delta, odd: xi;
// per-step shfl_xor exchange). No LDS round-trip for the bulk traffic; loads
// overlap the unrolled scan. 3 barriers total.
__global__ __launch_bounds__(256, 4) void k_scan_p3_oi(
        float* xz, const float* __restrict__ xiT, const float* __restrict__ deltaT,
        const float* __restrict__ xdbc,
        const float* __restrict__ A_log, const float* __restrict__ Dp,
        const float* __restrict__ wTo, const float* __restrict__ wTi,
        float* __restrict__ tio, const float* __restrict__ h0g, int doB) {
    __shared__ __align__(16) float u_s[CLEN * 132];    // z -> gated y
    __shared__ __align__(16) float bc_s[CLEN * 36];    // dt|B|C
    __shared__ __align__(16) float t_s[CLEN * 68];
    long m0 = (long)blockIdx.x << 5;
    int tid = threadIdx.x;
    int di = tid >> 1;
    int odd = tid & 1;
    int dso = odd << 3;

    // own-column register staging: even lane = delta column, odd = xi column
    const float* colp = (odd ? xiT : deltaT) + (long)di * MM + m0;
    float4 a4[8];
    #pragma unroll
    for (int j = 0; j < 8; ++j) a4[j] = *(const float4*)&colp[j << 2];

    // stage z into u_s (row-major, coalesced)
    #pragma unroll
    for (int ii = 0; ii < 4; ++ii) {
        int i = tid + (ii << 8);
        int r = i >> 5, c4 = (i & 31) << 2;
        *(float4*)&u_s[r * 132 + c4] = *(const float4*)&xz[((m0 + r) << 8) + DIM + c4];
    }
    // stage dt|B|C
    for (int i = tid; i < CLEN * 9; i += 256) {
        int r = i / 9, c4 = (i - r * 9) << 2;
        *(float4*)&bc_s[r * 36 + c4] = *(const float4*)&xdbc[(m0 + r) * 36 + c4];
    }
    // per-thread scan constants + h0
    float4 al0 = *(const float4*)&A_log[(di << 4) + dso];
    float4 al1 = *(const float4*)&A_log[(di << 4) + dso + 4];
    float Av[8] = { -expf(al0.x), -expf(al0.y), -expf(al0.z), -expf(al0.w),
                    -expf(al1.x), -expf(al1.y), -expf(al1.z), -expf(al1.w) };
    float Dv = Dp[di];
    long o = ((long)blockIdx.x << 11) + (di << 4) + dso;
    float4 h04 = *(const float4*)&h0g[o];
    float4 h14 = *(const float4*)&h0g[o + 4];
    float h[8] = { h04.x, h04.y, h04.z, h04.w, h14.x, h14.y, h14.z, h14.w };
    __syncthreads();

    // 32-step scan from registers, fully unrolled, gating fused
    #pragma unroll
    for (int i = 0; i < CLEN; ++i) {
        float own = A4GET(a4, i);
        float oth = __shfl_xor(own, 1);
        float d = odd ? oth : own;
        float u = odd ? own : oth;
        float du = d * u;
        const float* bc = &bc_s[i * 36];
        float4 B0 = *(const float4*)&bc[DTRK + dso];
        float4 B1 = *(const float4*)&bc[DTRK + dso + 4];
        float4 C0 = *(const float4*)&bc[DTRK + DSN + dso];
        float4 C1 = *(const float4*)&bc[DTRK + DSN + dso + 4];
        float a0 = __expf(d * Av[0]); h[0] = a0 * h[0] + du * B0.x;
        float a1 = __expf(d * Av[1]); h[1] = a1 * h[1] + du * B0.y;
        float a2 = __expf(d * Av[2]); h[2] = a2 * h[2] + du * B0.z;
        float a3 = __expf(d * Av[3]); h[3] = a3 * h[3] + du * B0.w;
        float a4s = __expf(d * Av[4]); h[4] = a4s * h[4] + du * B1.x;
        float a5 = __expf(d * Av[5]); h[5] = a5 * h[5] + du * B1.y;
        float a6 = __expf(d * Av[6]); h[6] = a6 * h[6] + du * B1.z;
        float a7 = __expf(d * Av[7]); h[7] = a7 * h[7] + du * B1.w;
        float yp = h[0] * C0.x + h[1] * C0.y + h[2] * C0.z + h[3] * C0.w
                 + h[4] * C1.x + h[5] * C1.y + h[6] * C1.z + h[7] * C1.w;
        yp += __shfl_xor(yp, 1);
        if (!odd) {
            float z = u_s[i * 132 + di];
            u_s[i * 132 + di] = (yp + u * Dv) * (z / (1.f + __expf(-z)));
        }
    }
    __syncthreads();

    // out_proj + residual: 32x64, K=128. thread = (2 rows, 4 cols)
    {
        int rg = tid >> 4, cg = tid & 15;
        int n0 = cg << 2;
        float acc[2][4] = {};
        for (int k4 = 0; k4 < 32; ++k4) {
            float4 a0 = *(const float4*)&u_s[(rg << 1) * 132 + (k4 << 2)];
            float4 a1 = *(const float4*)&u_s[((rg << 1) + 1) * 132 + (k4 << 2)];
            #pragma unroll
            for (int kk = 0; kk < 4; ++kk) {
                const float* wr = wTo + (((k4 << 2) + kk) << 6) + n0;
                float4 w0 = *(const float4*)&wr[0];
                float av0 = (kk == 0) ? a0.x : (kk == 1) ? a0.y : (kk == 2) ? a0.z : a0.w;
                float av1 = (kk == 0) ? a1.x : (kk == 1) ? a1.y : (kk == 2) ? a1.z : a1.w;
                acc[0][0] += av0 * w0.x; acc[0][1] += av0 * w0.y;
                acc[0][2] += av0 * w0.z; acc[0][3] += av0 * w0.w;
                acc[1][0] += av1 * w0.x; acc[1][1] += av1 * w0.y;
                acc[1][2] += av1 * w0.z; acc[1][3] += av1 * w0.w;
            }
        }
        #pragma unroll
        for (int r2 = 0; r2 < 2; ++r2) {
            long m = m0 + (rg << 1) + r2;
            float4 tv = *(const float4*)&tio[(m << 6) + n0];
            tv.x += acc[r2][0]; tv.y += acc[r2][1];
            tv.z += acc[r2][2]; tv.w += acc[r2][3];
            *(float4*)&tio[(m << 6) + n0] = tv;
            *(float4*)&t_s[((rg << 1) + r2) * 68 + n0] = tv;
        }
    }
    if (!doB) return;
    __syncthreads();

    // in_proj (next layer): 32x256, K=64. thread = (4 rows, 8 cols); in-place xz
    {
        int rg = tid >> 5, cgn = tid & 31;
        int n0 = cgn << 3;
        float acc[4][8] = {};
        for (int k4 = 0; k4 < 16; ++k4) {
            float4 a[4];
            #pragma unroll
            for (int r2 = 0; r2 < 4; ++r2)
                a[r2] = *(const float4*)&t_s[((rg << 2) + r2) * 68 + (k4 << 2)];
            #pragma unroll
            for (int kk = 0; kk < 4; ++kk) {
                const float* wr = wTi + (((k4 << 2) + kk) << 8) + n0;
                float4 w0 = *(const float4*)&wr[0];
                float4 w1 = *(const float4*)&wr[4];
                #pragma unroll
                for (int r2 = 0; r2 < 4; ++r2) {
                    float av = (kk == 0) ? a[r2].x : (kk == 1) ? a[r2].y
                             : (kk == 2) ? a[r2].z : a[r2].w;
                    acc[r2][0] += av * w0.x; acc[r2][1] += av * w0.y;
                    acc[r2][2] += av * w0.z; acc[r2][3] += av * w0.w;
                    acc[r2][4] += av * w1.x; acc[r2][5] += av * w1.y;
                    acc[r2][6] += av * w1.z; acc[r2][7] += av * w1.w;
                }
            }
        }
        #pragma unroll
        for (int r2 = 0; r2 < 4; ++r2) {
            long m = m0 + (rg << 2) + r2;
            *(float4*)&xz[(m << 8) + n0]     = make_float4(acc[r2][0], acc[r2][1], acc[r2][2], acc[r2][3]);
            *(float4*)&xz[(m << 8) + n0 + 4] = make_float4(acc[r2][4], acc[r2][5], acc[r2][6], acc[r2][7]);
        }
    }
}

// ---------------- decoder conv1 + fused BN-stat partials ----------------
__global__ __launch_bounds__(256, 1) void k_dec1_new(const float* __restrict__ tin,
                                                     const float* __restrict__ wT,
                                                     const float* __restrict__ bias,
                                                     float* __restrict__ out,
                                                     float* __restrict__ stats2) {
    __shared__ __align__(16) float x_s[64 * 132];
    __shared__ __align__(16) float w_s[4 * 4608];
    int tile = blockIdx.x;
    int b = blockIdx.y;
    int ty0 = (tile >> 3) << 3;
    int tx0 = (tile & 7) << 3;
    int tid = threadIdx.x;
    int wv = tid >> 6;
    int lane = tid & 63;
    int r = lane >> 3;
    int cg = lane & 7;

    for (int i = tid; i < 6400; i += 256) {
        int pl = i >> 6;
        int c = i & 63;
        int py = pl / 10, px = pl - py * 10;
        int ih = ty0 + py - 1, iw = tx0 + px - 1;
        float v = 0.f;
        if (ih >= 0 && ih < HH && iw >= 0 && iw < WWD)
            v = tin[(((long)((b << 12) + (ih << 6) + iw)) << 6) + c];
        x_s[c * 132 + py * 12 + px] = v;
    }
    float* myw = &w_s[wv * 4608];
    const float* gw = wT + (wv * 16) * 576;
    float4 pref[18];
    #pragma unroll
    for (int i = 0; i < 18; ++i)
        pref[i] = *(const float4*)&gw[(i * 64 + lane) * 4];
    #pragma unroll
    for (int i = 0; i < 18; ++i)
        *(float4*)&myw[(i * 64 + lane) * 4] = pref[i];
    __syncthreads();

    float acc[8][8] = {};
    #pragma unroll
    for (int ch = 0; ch < 2; ++ch) {
        if (ch == 0) {
            const float* gw1 = wT + (wv * 16 + 8) * 576;
            #pragma unroll
            for (int i = 0; i < 18; ++i)
                pref[i] = *(const float4*)&gw1[(i * 64 + lane) * 4];
        }
        for (int cl = 0; cl < 8; ++cl) {
            int cib = wv * 16 + ch * 8 + cl;
            float xrow[3][10];
            #pragma unroll
            for (int kh = 0; kh < 3; ++kh) {
                const float* xr = &x_s[cib * 132 + (r + kh) * 12];
                float4 a0 = *(const float4*)&xr[0];
                float4 a1 = *(const float4*)&xr[4];
                float2 a2 = *(const float2*)&xr[8];
                xrow[kh][0] = a0.x; xrow[kh][1] = a0.y; xrow[kh][2] = a0.z; xrow[kh][3] = a0.w;
                xrow[kh][4] = a1.x; xrow[kh][5] = a1.y; xrow[kh][6] = a1.z; xrow[kh][7] = a1.w;
                xrow[kh][8] = a2.x; xrow[kh][9] = a2.y;
            }
            const float* wp = &myw[cl * 576];
            #pragma unroll
            for (int kh = 0; kh < 3; ++kh) {
                #pragma unroll
                for (int kw = 0; kw < 3; ++kw) {
                    const float* wp2 = wp + (kh * 3 + kw) * 64 + (cg << 3);
                    float4 wa = *(const float4*)&wp2[0];
                    float4 wb = *(const float4*)&wp2[4];
                    #pragma unroll
                    for (int j = 0; j < 8; ++j) {
                        float xv = xrow[kh][kw + j];
                        acc[j][0] += xv * wa.x; acc[j][1] += xv * wa.y;
                        acc[j][2] += xv * wa.z; acc[j][3] += xv * wa.w;
                        acc[j][4] += xv * wb.x; acc[j][5] += xv * wb.y;
                        acc[j][6] += xv * wb.z; acc[j][7] += xv * wb.w;
                    }
                }
            }
        }
        if (ch == 0) {
            #pragma unroll
            for (int i = 0; i < 18; ++i)
                *(float4*)&myw[(i * 64 + lane) * 4] = pref[i];
        }
    }

    #pragma unroll
    for (int j = 0; j < 8; ++j) {
        *(float4*)&myw[lane * 68 + (j << 3)]     = make_float4(acc[j][0], acc[j][1], acc[j][2], acc[j][3]);
        *(float4*)&myw[lane * 68 + (j << 3) + 4] = make_float4(acc[j][4], acc[j][5], acc[j][6], acc[j][7]);
    }
    __syncthreads();

    float bv = bias[lane];
    float ssum = 0.f, ssq = 0.f;
    #pragma unroll
    for (int pp = 0; pp < 16; ++pp) {
        int pr = (wv << 1) + (pp >> 3);
        int pc = pp & 7;
        int ol = (pr << 3) + (lane >> 3);
        int ix = (pc << 3) + (lane & 7);
        float s = w_s[ol * 68 + ix] + w_s[4608 + ol * 68 + ix]
                + w_s[9216 + ol * 68 + ix] + w_s[13824 + ol * 68 + ix] + bv;
        out[(((long)((b << 12) + ((ty0 + pr) << 6) + tx0 + pc)) << 6) + lane] = s;
        ssum += s; ssq += s * s;
    }
    float* red = x_s;
    red[(wv << 6) + lane] = ssum;
    red[256 + (wv << 6) + lane] = ssq;
    __syncthreads();
    if (tid < 64) {
        float a = red[tid] + red[64 + tid] + red[128 + tid] + red[192 + tid];
        float q = red[256 + tid] + red[320 + tid] + red[384 + tid] + red[448 + tid];
        atomicAdd(&stats2[tid], a);
        atomicAdd(&stats2[64 + tid], q);
    }
}

// ------- decoder conv2 FUSED with BN+ReLU (inline stats) -------
__global__ void k_dec2_fused(const float* __restrict__ src, const float* __restrict__ stats2,
                             const float* __restrict__ g, const float* __restrict__ be,
                             const float* __restrict__ wT, const float* __restrict__ bias,
                             float* __restrict__ out) {
    __shared__ float x_s[64 * 101];
    __shared__ float w_s[64 * NFC * 12];
    __shared__ float sc_s[64];
    __shared__ float sh_s[64];
    int tile = blockIdx.x;
    int b = blockIdx.y;
    int ty0 = (tile >> 3) << 3;
    int tx0 = (tile & 7) << 3;
    int tid = threadIdx.x;

    if (tid < 64) {
        float m = stats2[tid] * (1.f / 16384.f);
        float var = stats2[64 + tid] * (1.f / 16384.f) - m * m;
        float s = g[tid] * rsqrtf(var + 1e-5f);
        sc_s[tid] = s;
        sh_s[tid] = be[tid] - m * s;
    }
    for (int i = tid; i < 64 * NFC * 12; i += 256)
        w_s[i] = wT[i];
    __syncthreads();

    for (int i = tid; i < 6400; i += 256) {
        int pl = i >> 6;
        int c = i & 63;
        int py = pl / 10, px = pl - py * 10;
        int ih = ty0 + py - 1, iw = tx0 + px - 1;
        float v = 0.f;
        if (ih >= 0 && ih < HH && iw >= 0 && iw < WWD) {
            v = src[((long)((b << 12) + (ih << 6) + iw)) * 64 + c];
            v = fmaxf(v * sc_s[c] + sh_s[c], 0.f);
        }
        x_s[c * 101 + pl] = v;
    }
    __syncthreads();

    int px = tid & 63;
    int py = px >> 3, pxx = px & 7;
    int cog = tid >> 6;
    float acc[3] = {0.f, 0.f, 0.f};
    int nco = (cog < 2) ? 3 : 2;

    for (int ci = 0; ci < 64; ++ci) {
        const float* xr = &x_s[ci * 101 + py * 10 + pxx];
        float xv[9];
        #pragma unroll
        for (int kh = 0; kh < 3; ++kh)
            #pragma unroll
            for (int kw = 0; kw < 3; ++kw)
                xv[kh * 3 + kw] = xr[kh * 10 + kw];
        #pragma unroll
        for (int j = 0; j < 3; ++j) {
            if (j >= nco) break;
            int co = cog + (j << 2);
            const float* wp = &w_s[(ci * NFC + co) * 12];
            float4 w0 = *(const float4*)&wp[0];
            float4 w1 = *(const float4*)&wp[4];
            float  w8 = wp[8];
            acc[j] += xv[0] * w0.x + xv[1] * w0.y + xv[2] * w0.z + xv[3] * w0.w
                    + xv[4] * w1.x + xv[5] * w1.y + xv[6] * w1.z + xv[7] * w1.w
                    + xv[8] * w8;
        }
    }
    int hw = ((ty0 + py) << 6) + tx0 + pxx;
    #pragma unroll
    for (int j = 0; j < 3; ++j) {
        if (j >= nco) break;
        int co = cog + (j << 2);
        out[((long)(b * NFC + co) << 12) + hw] = acc[j] + bias[co];
    }
}

extern "C" void kernel_launch(void* const* d_in, const int* in_sizes, int n_in,
                              void* d_out, int out_size, void* d_ws, size_t ws_size,
                              hipStream_t stream) {
    const float* x       = (const float*)d_in[0];
    const float* enc_w   = (const float*)d_in[1];
    const float* enc_b   = (const float*)d_in[2];
    const float* enc_g   = (const float*)d_in[3];
    const float* enc_be  = (const float*)d_in[4];
    const float* in_proj = (const float*)d_in[5];
    const float* conv_w  = (const float*)d_in[6];
    const float* conv_b  = (const float*)d_in[7];
    const float* x_proj  = (const float*)d_in[8];
    const float* dt_w    = (const float*)d_in[9];
    const float* dt_b    = (const float*)d_in[10];
    const float* A_log   = (const float*)d_in[11];
    const float* Dp      = (const float*)d_in[12];
    const float* out_prj = (const float*)d_in[13];
    const float* dec1_w  = (const float*)d_in[14];
    const float* dec1_b  = (const float*)d_in[15];
    const float* dec1_g  = (const float*)d_in[16];
    const float* dec1_be = (const float*)d_in[17];
    const float* dec2_w  = (const float*)d_in[18];
    const float* dec2_b  = (const float*)d_in[19];
    float* out = (float*)d_out;

    float* ws = (float*)d_ws;
    size_t off = 0;
    float* conv_buf  = ws + off; off += 1048576;  // enc out / dec scratch
    float* stats     = ws + off; off += 128;
    float* stats2    = ws + off; off += 128;
    float* wT1       = ws + off; off += 36864;
    float* wT2       = ws + off; off += 7680;
    float* wTin      = ws + off; off += 65536;
    float* wTout     = ws + off; off += 32768;
    float* t_buf     = ws + off; off += 1048576;
    float* xz_buf    = ws + off; off += 4194304;
    float* xiT_buf   = ws + off; off += 2097152;  // [di][m] transposed
    float* deltaT_buf= ws + off; off += 2097152;  // [di][m] transposed
    float* xdbc_buf  = ws + off; off += 589824;
    float* Pb        = ws + off; off += 1048576;  // 32-gran aggregates
    float* Sb        = ws + off; off += 1048576;  // 32-gran; becomes h0 after p2
    (void)ws_size; (void)in_sizes; (void)n_in; (void)out_size;

    // prep: transposes + zero stats (runs every launch; graph-safe)
    k_prep_all<<<560, 256, 0, stream>>>(in_proj, out_prj, dec1_w, dec2_w,
                                        wTin, wTout, wT1, wT2, stats, stats2);

    // encoder (BN-apply fused into first in_proj)
    k_enc_conv<<<4096, 256, 0, stream>>>(x, enc_w, enc_b, conv_buf, stats);

    // first in_proj
    k_gemm_in_bn<<<256, 256, 0, stream>>>(conv_buf, stats, enc_g, enc_be, wTin,
                                          t_buf, xz_buf);

    // mamba layers (CLEN=32 -> 512 blocks per kernel)
    for (int i = 0; i < NLAYER; ++i) {
        int doB = (i < NLAYER - 1) ? 1 : 0;
        k_xproj_fused<<<512, 512, 0, stream>>>(
            xz_buf, conv_w + i * DIM * DCN, conv_b + i * DIM, x_proj + i * 36 * DIM,
            dt_w + i * DIM * DTRK, dt_b + i * DIM, A_log + i * DIM * DSN,
            xiT_buf, deltaT_buf, xdbc_buf, Pb, Sb);
        k_scan_p2<<<32, 256, 0, stream>>>(Pb, Sb);
        k_scan_p3_oi<<<512, 256, 0, stream>>>(
            xz_buf, xiT_buf, deltaT_buf, xdbc_buf,
            A_log + i * DIM * DSN, Dp + i * DIM,
            wTout + i * 8192, wTin + ((i + 1) & 3) * 16384,
            t_buf, Sb, doB);
    }

    // decoder
    dim3 dg1(64, BB);
    k_dec1_new<<<dg1, 256, 0, stream>>>(t_buf, wT1, dec1_b, conv_buf, stats2);
    k_dec2_fused<<<dg1, 256, 0, stream>>>(conv_buf, stats2, dec1_g, dec1_be, wT2, dec2_b, out);
}